// Round 12
// baseline (277.452 us; speedup 1.0000x reference)
//
#include <hip/hip_runtime.h>
#include <hip/hip_bf16.h>
#include <stdint.h>
#include <type_traits>

typedef unsigned short u16;
typedef __bf16 bf16x8 __attribute__((ext_vector_type(8)));
typedef float f32x4 __attribute__((ext_vector_type(4)));

#define M_TOT 8192   // B*S
#define N_TOT 4096   // reduction dim
#define K_TOT 4096   // output dim
#define BM 256
#define BN 256
#define BK 64
#define NT 64        // N_TOT / BK

// LDS geometry in u16 elements: [slot][A:2 halves | B:2 halves][128][64]
#define HALF_EL 8192     // 128 rows * 64 cols
#define B_OFF   16384
#define SLOT_EL 32768    // 64 KiB per slot
#define SLOT_BYTES 65536

#define CVT_BLOCKS 16384   // M_TOT*N_TOT/8/256
#define DEQ_BLOCKS 8192    // K_TOT*N_TOT/8/256

template <int V> using ic = std::integral_constant<int, V>;
template <bool V> using bc = std::integral_constant<bool, V>;

__device__ __forceinline__ u16 f2bf(float f) {
    union { float f; uint32_t u; } v; v.f = f;
    uint32_t u = v.u;
    return (u16)((u + 0x7fffu + ((u >> 16) & 1u)) >> 16);
}

// ---- fused pre-pass: blocks [0,CVT) convert x; [CVT, CVT+DEQ) dequantize W ----
__global__ __launch_bounds__(256) void prep_kernel(const float* __restrict__ x,
                                                   u16* __restrict__ xb,
                                                   const int* __restrict__ wq,
                                                   const float* __restrict__ scales,
                                                   const float* __restrict__ zeros,
                                                   const float* __restrict__ mu1,
                                                   const float* __restrict__ mu2,
                                                   u16* __restrict__ wb) {
    const int b = blockIdx.x;
    if (b < CVT_BLOCKS) {
        const int i = b * 256 + threadIdx.x;
        const float4* p = (const float4*)x + (size_t)i * 2;
        float4 v0 = p[0], v1 = p[1];
        uint4 o;
        o.x = (uint32_t)f2bf(v0.x) | ((uint32_t)f2bf(v0.y) << 16);
        o.y = (uint32_t)f2bf(v0.z) | ((uint32_t)f2bf(v0.w) << 16);
        o.z = (uint32_t)f2bf(v1.x) | ((uint32_t)f2bf(v1.y) << 16);
        o.w = (uint32_t)f2bf(v1.z) | ((uint32_t)f2bf(v1.w) << 16);
        *((uint4*)(xb + (size_t)i * 8)) = o;
    } else {
        const int i = (b - CVT_BLOCKS) * 256 + threadIdx.x;
        const int k  = i >> 9;
        const int n0 = (i & 511) << 3;
        const int g  = n0 >> 6;
        const float z  = zeros[k * 64 + g];
        const float sm = scales[k * 64 + g] * mu2[k];
        const int4* qp = (const int4*)(wq + (size_t)k * N_TOT + n0);
        int4 q0 = qp[0], q1 = qp[1];
        const float4* mp = (const float4*)(mu1 + n0);
        float4 u0 = mp[0], u1 = mp[1];
        uint4 o;
        o.x = (uint32_t)f2bf(((float)q0.x - z) * sm * u0.x) |
              ((uint32_t)f2bf(((float)q0.y - z) * sm * u0.y) << 16);
        o.y = (uint32_t)f2bf(((float)q0.z - z) * sm * u0.z) |
              ((uint32_t)f2bf(((float)q0.w - z) * sm * u0.w) << 16);
        o.z = (uint32_t)f2bf(((float)q1.x - z) * sm * u1.x) |
              ((uint32_t)f2bf(((float)q1.y - z) * sm * u1.y) << 16);
        o.w = (uint32_t)f2bf(((float)q1.z - z) * sm * u1.z) |
              ((uint32_t)f2bf(((float)q1.w - z) * sm * u1.w) << 16);
        *((uint4*)(wb + (size_t)k * N_TOT + n0)) = o;
    }
}

// ---- main GEMM: one-ahead feed + m201 per-phase barrier discipline ------------
// 8 waves (2M x 4N), per-wave out 128x64, BK=64, double-buffered LDS.
// Quadrants: q0=(A0,B0) q1=(A0,B1) q2=(A1,B1) q3=(A1,B0).
// Per phase: {issue ds_read (one-ahead) + stage} -> barrier -> MFMA -> barrier.
// NO explicit lgkm anywhere (compiler emits counted waits at consumers, one
// full MFMA cluster after issue). Reads:
//   p0: bf1(t)        stage A1,B1(t+1)->S^1      MFMA q0(afLo,bf0)
//   p1: afHi(t)                                  MFMA q1(afLo,bf1); vmcnt(4)
//   p2: afLo(t+1)@S^1 stage A0,B0(t+2)->S        MFMA q2(afHi,bf1)
//   p3: [MFMA q3(afHi,bf0) first]; bf0(t+1)@S^1; vmcnt(4)
// vmcnt derivation (unchanged from R11): at p1-end outstanding = {t-1.p2}(4)
// + {t.p0}(4) -> vmcnt(4) drains t-1.p2 = A0B0(t+1) for p2's read. At p3-end
// outstanding = {t.p0}(4) + {t.p2}(4) -> vmcnt(4) drains t.p0 = A1B1(t+1)
// for t+1's p0/p1 reads. 3-phase flight > HBM latency.
// WAR legality: stage A1B1->S^1 @p0 follows t-1's p3-end barrier, after
// afHi/bf1(t-1) were consumed by t-1's q2/q3. Stage A0B0->S @p2 follows t's
// p1-end barrier, after afLo/bf0(t) consumed by q0/q1. bf0' read sits after
// q3 (bf0 is q3's operand).
// LDS XOR swizzle (proven R2): physical col = logical ^ ((row&7)*8 elems).
__global__ __launch_bounds__(512, 2) void gemm_kernel(const u16* __restrict__ Xb,
                                                      const u16* __restrict__ Wb,
                                                      const float* __restrict__ bias,
                                                      float* __restrict__ out) {
    __shared__ __align__(16) u16 lds[2 * SLOT_EL];   // 128 KiB

    // XCD-bijective swizzle: nwg = 512, divisible by 8
    const int bid = blockIdx.x;
    const int cpx = gridDim.x >> 3;
    const int swz = (bid & 7) * cpx + (bid >> 3);
    const int bm = swz >> 4;    // 32 M-tiles
    const int bn = swz & 15;    // 16 out-tiles

    const int tid  = threadIdx.x;
    const int w    = tid >> 6;
    const int lane = tid & 63;
    const int wm = w >> 2, wn = w & 3;

    // staging: lane l, issue i covers LDS row (w*16 + i*8 + (l>>3)), physical
    // col (l&7)*16B; global col pre-swizzled: ((l&7)^(l>>3))*8 elems.
    const int scol = (((lane & 7) ^ (lane >> 3)) << 3);
    const u16* aT = Xb + (size_t)(bm * BM + w * 16 + (lane >> 3)) * N_TOT + scol;
    const u16* bT = Wb + (size_t)(bn * BN + w * 16 + (lane >> 3)) * N_TOT + scol;

    u16* const sdA = &lds[w * 1024];
    u16* const sdB = &lds[B_OFF + w * 1024];

    auto gload = [](const u16* s, u16* d) {
        __builtin_amdgcn_global_load_lds(
            (const __attribute__((address_space(1))) uint32_t*)s,
            (__attribute__((address_space(3))) uint32_t*)d, 16, 0, 0);
    };
    auto stA = [&](auto SlC, auto Hc, auto Dc) {
        const u16* s = aT + (size_t)(Hc.value * 128) * N_TOT + Dc.value;
        u16* d = sdA + SlC.value * SLOT_EL + Hc.value * HALF_EL;
        gload(s, d); gload(s + (size_t)8 * N_TOT, d + 512);
    };
    auto stB = [&](auto SlC, auto Hc, auto Dc) {
        const u16* s = bT + (size_t)(Hc.value * 128) * N_TOT + Dc.value;
        u16* d = sdB + SlC.value * SLOT_EL + Hc.value * HALF_EL;
        gload(s, d); gload(s + (size_t)8 * N_TOT, d + 512);
    };

    // toggling LDS read byte-offsets (current slot); ks0/ks1 variants
    const int cc0 = (((lane >> 4) << 3)) ^ ((lane & 7) << 3);
    const int rA  = ((wm << 4) + (lane & 15)) << 6;
    const int rB  = ((wn << 4) + (lane & 15)) << 6;
    int oAa = (rA + cc0) * 2;
    int oAb = (rA + (cc0 ^ 32)) * 2;
    int oBa = (B_OFF + rB + cc0) * 2;
    int oBb = (B_OFF + rB + (cc0 ^ 32)) * 2;
    const char* const ldsc = (const char*)lds;

    f32x4 acc[2][2][4][2] = {};
    bf16x8 afLo[4][2], afHi[4][2];   // [j][ks]
    bf16x8 bf0[2][2], bf1[2][2];     // [j2][ks]

    auto rd_afLo_next = [&]() {   // A half0 of NEXT tile (other slot)
        const int xa = oAa ^ SLOT_BYTES, xb2 = oAb ^ SLOT_BYTES;
        #pragma unroll
        for (int j = 0; j < 4; ++j) {
            afLo[j][0] = *(const bf16x8*)(ldsc + xa + j * 4096);
            afLo[j][1] = *(const bf16x8*)(ldsc + xb2 + j * 4096);
        }
    };
    auto rd_bf0_next = [&]() {    // B half0 of NEXT tile (other slot)
        const int xa = oBa ^ SLOT_BYTES, xb2 = oBb ^ SLOT_BYTES;
        #pragma unroll
        for (int j2 = 0; j2 < 2; ++j2) {
            bf0[j2][0] = *(const bf16x8*)(ldsc + xa + j2 * 8192);
            bf0[j2][1] = *(const bf16x8*)(ldsc + xb2 + j2 * 8192);
        }
    };
    auto rd_afHi_cur = [&]() {    // A half1 of CURRENT tile
        #pragma unroll
        for (int j = 0; j < 4; ++j) {
            afHi[j][0] = *(const bf16x8*)(ldsc + oAa + 16384 + j * 4096);
            afHi[j][1] = *(const bf16x8*)(ldsc + oAb + 16384 + j * 4096);
        }
    };
    auto rd_bf1_cur = [&]() {     // B half1 of CURRENT tile
        #pragma unroll
        for (int j2 = 0; j2 < 2; ++j2) {
            bf1[j2][0] = *(const bf16x8*)(ldsc + oBa + 16384 + j2 * 8192);
            bf1[j2][1] = *(const bf16x8*)(ldsc + oBb + 16384 + j2 * 8192);
        }
    };

    #define MFMA_CLUSTER(A, B, MH, NH)                                          \
        __builtin_amdgcn_s_setprio(1);                                          \
        _Pragma("unroll")                                                       \
        for (int ks = 0; ks < 2; ++ks)                                          \
            _Pragma("unroll")                                                   \
            for (int j = 0; j < 4; ++j)                                         \
                _Pragma("unroll")                                               \
                for (int j2 = 0; j2 < 2; ++j2)                                  \
                    acc[MH][NH][j][j2] = __builtin_amdgcn_mfma_f32_16x16x32_bf16(\
                        A[j][ks], B[j2][ks], acc[MH][NH][j][j2], 0, 0, 0);      \
        __builtin_amdgcn_s_setprio(0);

    auto vmw = [](auto Vc) {
        if constexpr (Vc.value == 4) asm volatile("s_waitcnt vmcnt(4)" ::: "memory");
        else if constexpr (Vc.value == 0) asm volatile("s_waitcnt vmcnt(0)" ::: "memory");
    };

    // one K-tile, m201 per-phase barrier discipline
    auto ktile = [&](auto SlC, auto St0, auto St2, auto RdN,
                     auto V1c, auto V3c, auto D0, auto D1) {
        constexpr int SL = SlC.value;
        // ---- p0 ----
        rd_bf1_cur();
        if constexpr (St0.value) { stA(ic<SL ^ 1>{}, ic<1>{}, D0);
                                   stB(ic<SL ^ 1>{}, ic<1>{}, D0); }
        __builtin_amdgcn_s_barrier();
        MFMA_CLUSTER(afLo, bf0, 0, 0)
        __builtin_amdgcn_s_barrier();
        // ---- p1 ----
        rd_afHi_cur();
        __builtin_amdgcn_s_barrier();
        MFMA_CLUSTER(afLo, bf1, 0, 1)
        vmw(V1c);
        __builtin_amdgcn_s_barrier();
        // ---- p2 ----
        if constexpr (RdN.value) rd_afLo_next();
        if constexpr (St2.value) { stA(SlC, ic<0>{}, D1);
                                   stB(SlC, ic<0>{}, D1); }
        __builtin_amdgcn_s_barrier();
        MFMA_CLUSTER(afHi, bf1, 1, 1)
        __builtin_amdgcn_s_barrier();
        // ---- p3 ---- (MFMA first: bf0 is q3's live operand)
        MFMA_CLUSTER(afHi, bf0, 1, 0)
        if constexpr (RdN.value) rd_bf0_next();
        vmw(V3c);
        __builtin_amdgcn_s_barrier();
        // toggle read bases to the other slot
        oAa ^= SLOT_BYTES; oAb ^= SLOT_BYTES; oBa ^= SLOT_BYTES; oBb ^= SLOT_BYTES;
    };

    // prologue: stage tile0 full (8) + A0,B0(tile1) (4 = steady "t-1.p2"
    // residue); vmcnt(4) drains tile0; barrier; read tile0's q0 fragments.
    stA(ic<0>{}, ic<0>{}, ic<0>{});  stB(ic<0>{}, ic<0>{}, ic<0>{});
    stA(ic<0>{}, ic<1>{}, ic<0>{});  stB(ic<0>{}, ic<1>{}, ic<0>{});
    stA(ic<1>{}, ic<0>{}, ic<BK>{}); stB(ic<1>{}, ic<0>{}, ic<BK>{});
    asm volatile("s_waitcnt vmcnt(4)" ::: "memory");
    __builtin_amdgcn_s_barrier();
    {   // initial q0 fragments from slot 0
        #pragma unroll
        for (int j = 0; j < 4; ++j) {
            afLo[j][0] = *(const bf16x8*)(ldsc + oAa + j * 4096);
            afLo[j][1] = *(const bf16x8*)(ldsc + oAb + j * 4096);
        }
        #pragma unroll
        for (int j2 = 0; j2 < 2; ++j2) {
            bf0[j2][0] = *(const bf16x8*)(ldsc + oBa + j2 * 8192);
            bf0[j2][1] = *(const bf16x8*)(ldsc + oBb + j2 * 8192);
        }
    }

    // steady: 31 pairs = tiles 0..61
    for (int it = 0; it < 31; ++it) {
        ktile(ic<0>{}, bc<true>{}, bc<true>{}, bc<true>{},
              ic<4>{}, ic<4>{}, ic<BK>{}, ic<2 * BK>{});
        ktile(ic<1>{}, bc<true>{}, bc<true>{}, bc<true>{},
              ic<4>{}, ic<4>{}, ic<2 * BK>{}, ic<3 * BK>{});
        aT += 2 * BK;
        bT += 2 * BK;
    }
    // tile 62: stage A1B1(63) @p0 only; V1=4 drains A0B0(63) [from 61.p2];
    // V3=0 drains A1B1(63) before tile 63's reads.
    ktile(ic<0>{}, bc<true>{}, bc<false>{}, bc<true>{},
          ic<4>{}, ic<0>{}, ic<BK>{}, ic<0>{});
    // tile 63: no stages, no ahead-reads, no waits
    ktile(ic<1>{}, bc<false>{}, bc<false>{}, bc<false>{},
          ic<-1>{}, ic<-1>{}, ic<0>{}, ic<0>{});

    #undef MFMA_CLUSTER

    // epilogue: C/D layout col = lane&15 (out-dim), row = (lane>>4)*4 + rr (M)
    #pragma unroll
    for (int mh_ = 0; mh_ < 2; ++mh_)
        #pragma unroll
        for (int j = 0; j < 4; ++j)
            #pragma unroll
            for (int rr = 0; rr < 4; ++rr) {
                const int row = bm * BM + mh_ * 128 + j * 32 + wm * 16 + ((lane >> 4) << 2) + rr;
                float* orow = out + (size_t)row * K_TOT;
                #pragma unroll
                for (int nh_ = 0; nh_ < 2; ++nh_)
                    #pragma unroll
                    for (int j2 = 0; j2 < 2; ++j2) {
                        const int col = bn * BN + nh_ * 128 + j2 * 64 + wn * 16 + (lane & 15);
                        orow[col] = acc[mh_][nh_][j][j2][rr] + bias[col];
                    }
            }
}

extern "C" void kernel_launch(void* const* d_in, const int* in_sizes, int n_in,
                              void* d_out, int out_size, void* d_ws, size_t ws_size,
                              hipStream_t stream) {
    const float* x      = (const float*)d_in[0];
    const float* scales = (const float*)d_in[1];
    const float* zeros  = (const float*)d_in[2];
    const float* mu1    = (const float*)d_in[3];
    const float* mu2    = (const float*)d_in[4];
    const float* bias   = (const float*)d_in[5];
    const int*   wq     = (const int*)d_in[6];
    float* out = (float*)d_out;

    u16* xb = (u16*)d_ws;                                 // 64 MiB
    u16* wb = (u16*)d_ws + (size_t)M_TOT * N_TOT;         // 32 MiB

    prep_kernel<<<CVT_BLOCKS + DEQ_BLOCKS, 256, 0, stream>>>(
        x, xb, wq, scales, zeros, mu1, mu2, wb);
    gemm_kernel<<<(M_TOT / BM) * (K_TOT / BN), 512, 0, stream>>>(xb, wb, bias, out);
}

// Round 13
// 264.861 us; speedup vs baseline: 1.0475x; 1.0475x over previous
//
#include <hip/hip_runtime.h>
#include <hip/hip_bf16.h>
#include <stdint.h>
#include <type_traits>

typedef unsigned short u16;
typedef __bf16 bf16x8 __attribute__((ext_vector_type(8)));
typedef float f32x4 __attribute__((ext_vector_type(4)));

#define M_TOT 8192   // B*S
#define N_TOT 4096   // reduction dim
#define K_TOT 4096   // output dim
#define BM 256
#define BN 256
#define BK 64
#define NT 64        // N_TOT / BK

// LDS geometry in u16 elements: [slot][A:2 halves | B:2 halves][128][64]
#define HALF_EL 8192     // 128 rows * 64 cols
#define B_OFF   16384
#define SLOT_EL 32768    // 64 KiB per slot
#define SLOT_BYTES 65536

#define CVT_BLOCKS 16384   // M_TOT*N_TOT/8/256
#define DEQ_BLOCKS 8192    // K_TOT*N_TOT/8/256

template <int V> using ic = std::integral_constant<int, V>;
template <bool V> using bc = std::integral_constant<bool, V>;

__device__ __forceinline__ u16 f2bf(float f) {
    union { float f; uint32_t u; } v; v.f = f;
    uint32_t u = v.u;
    return (u16)((u + 0x7fffu + ((u >> 16) & 1u)) >> 16);
}

// ---- fused pre-pass: blocks [0,CVT) convert x; [CVT, CVT+DEQ) dequantize W ----
__global__ __launch_bounds__(256) void prep_kernel(const float* __restrict__ x,
                                                   u16* __restrict__ xb,
                                                   const int* __restrict__ wq,
                                                   const float* __restrict__ scales,
                                                   const float* __restrict__ zeros,
                                                   const float* __restrict__ mu1,
                                                   const float* __restrict__ mu2,
                                                   u16* __restrict__ wb) {
    const int b = blockIdx.x;
    if (b < CVT_BLOCKS) {
        const int i = b * 256 + threadIdx.x;
        const float4* p = (const float4*)x + (size_t)i * 2;
        float4 v0 = p[0], v1 = p[1];
        uint4 o;
        o.x = (uint32_t)f2bf(v0.x) | ((uint32_t)f2bf(v0.y) << 16);
        o.y = (uint32_t)f2bf(v0.z) | ((uint32_t)f2bf(v0.w) << 16);
        o.z = (uint32_t)f2bf(v1.x) | ((uint32_t)f2bf(v1.y) << 16);
        o.w = (uint32_t)f2bf(v1.z) | ((uint32_t)f2bf(v1.w) << 16);
        *((uint4*)(xb + (size_t)i * 8)) = o;
    } else {
        const int i = (b - CVT_BLOCKS) * 256 + threadIdx.x;
        const int k  = i >> 9;
        const int n0 = (i & 511) << 3;
        const int g  = n0 >> 6;
        const float z  = zeros[k * 64 + g];
        const float sm = scales[k * 64 + g] * mu2[k];
        const int4* qp = (const int4*)(wq + (size_t)k * N_TOT + n0);
        int4 q0 = qp[0], q1 = qp[1];
        const float4* mp = (const float4*)(mu1 + n0);
        float4 u0 = mp[0], u1 = mp[1];
        uint4 o;
        o.x = (uint32_t)f2bf(((float)q0.x - z) * sm * u0.x) |
              ((uint32_t)f2bf(((float)q0.y - z) * sm * u0.y) << 16);
        o.y = (uint32_t)f2bf(((float)q0.z - z) * sm * u0.z) |
              ((uint32_t)f2bf(((float)q0.w - z) * sm * u0.w) << 16);
        o.z = (uint32_t)f2bf(((float)q1.x - z) * sm * u1.x) |
              ((uint32_t)f2bf(((float)q1.y - z) * sm * u1.y) << 16);
        o.w = (uint32_t)f2bf(((float)q1.z - z) * sm * u1.z) |
              ((uint32_t)f2bf(((float)q1.w - z) * sm * u1.w) << 16);
        *((uint4*)(wb + (size_t)k * N_TOT + n0)) = o;
    }
}

// ---- main GEMM: one-ahead continuous-feed (EXACT R11 structure, measured 231us)
// 8 waves (2M x 4N), per-wave out 128x64, BK=64, double-buffered LDS.
// Quadrants: q0=(A0,B0) q1=(A0,B1) q2=(A1,B1) q3=(A1,B0).
// ONE-AHEAD: every read's consumer MFMA sits >=1 full cluster later; the
// COMPILER places counted lgkm waits there. No explicit lgkm anywhere.
//   p0: read bf1(t)       ; stage A1,B1(t+1)->S^1 ; MFMA q0(afLo,bf0)
//   p1: read afHi(t)      ;                       ; MFMA q1(afLo,bf1)
//       vmcnt(4) ; barrier ; sched_barrier
//   p2: read afLo(t+1)@S^1; stage A0,B0(t+2)->S   ; MFMA q2(afHi,bf1)
//   p3: MFMA q3(afHi,bf0) ; read bf0(t+1)@S^1
//       vmcnt(4) ; barrier ; sched_barrier
// vmcnt: at p1-end outstanding = {t-1.p2}(4) + {t.p0}(4) -> vmcnt(4) drains
// t-1.p2 = A0B0(t+1) for p2's read. At p3-end outstanding = {t.p0}(4) +
// {t.p2}(4) -> vmcnt(4) drains t.p0 = A1B1(t+1) for t+1's reads.
// WAR legality: stage A1B1->S^1 @p0 follows t-1's p3-end barrier (afHi/bf1 of
// t-1 consumed by its q2/q3); stage A0B0->S @p2 follows t's p1-end barrier
// (afLo/bf0 of t consumed by q0/q1). Race-sensitive reads follow an
// asm-"memory" vmcnt -> cannot hoist.
// LDS XOR swizzle (proven R2): physical col = logical ^ ((row&7)*8 elems).
__global__ __launch_bounds__(512, 2) void gemm_kernel(const u16* __restrict__ Xb,
                                                      const u16* __restrict__ Wb,
                                                      const float* __restrict__ bias,
                                                      float* __restrict__ out) {
    __shared__ __align__(16) u16 lds[2 * SLOT_EL];   // 128 KiB

    // XCD-bijective swizzle: nwg = 512, divisible by 8
    const int bid = blockIdx.x;
    const int cpx = gridDim.x >> 3;
    const int swz = (bid & 7) * cpx + (bid >> 3);
    const int bm = swz >> 4;    // 32 M-tiles
    const int bn = swz & 15;    // 16 out-tiles

    const int tid  = threadIdx.x;
    const int w    = tid >> 6;
    const int lane = tid & 63;
    const int wm = w >> 2, wn = w & 3;

    // staging: lane l, issue i covers LDS row (w*16 + i*8 + (l>>3)), physical
    // col (l&7)*16B; global col pre-swizzled: ((l&7)^(l>>3))*8 elems.
    const int scol = (((lane & 7) ^ (lane >> 3)) << 3);
    const u16* aT = Xb + (size_t)(bm * BM + w * 16 + (lane >> 3)) * N_TOT + scol;
    const u16* bT = Wb + (size_t)(bn * BN + w * 16 + (lane >> 3)) * N_TOT + scol;

    u16* const sdA = &lds[w * 1024];
    u16* const sdB = &lds[B_OFF + w * 1024];

    auto gload = [](const u16* s, u16* d) {
        __builtin_amdgcn_global_load_lds(
            (const __attribute__((address_space(1))) uint32_t*)s,
            (__attribute__((address_space(3))) uint32_t*)d, 16, 0, 0);
    };
    auto stA = [&](auto SlC, auto Hc, auto Dc) {
        const u16* s = aT + (size_t)(Hc.value * 128) * N_TOT + Dc.value;
        u16* d = sdA + SlC.value * SLOT_EL + Hc.value * HALF_EL;
        gload(s, d); gload(s + (size_t)8 * N_TOT, d + 512);
    };
    auto stB = [&](auto SlC, auto Hc, auto Dc) {
        const u16* s = bT + (size_t)(Hc.value * 128) * N_TOT + Dc.value;
        u16* d = sdB + SlC.value * SLOT_EL + Hc.value * HALF_EL;
        gload(s, d); gload(s + (size_t)8 * N_TOT, d + 512);
    };

    // toggling LDS read byte-offsets (current slot); ks0/ks1 variants
    const int cc0 = (((lane >> 4) << 3)) ^ ((lane & 7) << 3);
    const int rA  = ((wm << 4) + (lane & 15)) << 6;
    const int rB  = ((wn << 4) + (lane & 15)) << 6;
    int oAa = (rA + cc0) * 2;
    int oAb = (rA + (cc0 ^ 32)) * 2;
    int oBa = (B_OFF + rB + cc0) * 2;
    int oBb = (B_OFF + rB + (cc0 ^ 32)) * 2;
    const char* const ldsc = (const char*)lds;

    f32x4 acc[2][2][4][2] = {};
    bf16x8 afLo[4][2], afHi[4][2];   // [j][ks]
    bf16x8 bf0[2][2], bf1[2][2];     // [j2][ks]

    auto rd_afLo_next = [&]() {   // A half0 of NEXT tile (other slot)
        const int xa = oAa ^ SLOT_BYTES, xb2 = oAb ^ SLOT_BYTES;
        #pragma unroll
        for (int j = 0; j < 4; ++j) {
            afLo[j][0] = *(const bf16x8*)(ldsc + xa + j * 4096);
            afLo[j][1] = *(const bf16x8*)(ldsc + xb2 + j * 4096);
        }
    };
    auto rd_bf0_next = [&]() {    // B half0 of NEXT tile (other slot)
        const int xa = oBa ^ SLOT_BYTES, xb2 = oBb ^ SLOT_BYTES;
        #pragma unroll
        for (int j2 = 0; j2 < 2; ++j2) {
            bf0[j2][0] = *(const bf16x8*)(ldsc + xa + j2 * 8192);
            bf0[j2][1] = *(const bf16x8*)(ldsc + xb2 + j2 * 8192);
        }
    };
    auto rd_afHi_cur = [&]() {    // A half1 of CURRENT tile
        #pragma unroll
        for (int j = 0; j < 4; ++j) {
            afHi[j][0] = *(const bf16x8*)(ldsc + oAa + 16384 + j * 4096);
            afHi[j][1] = *(const bf16x8*)(ldsc + oAb + 16384 + j * 4096);
        }
    };
    auto rd_bf1_cur = [&]() {     // B half1 of CURRENT tile
        #pragma unroll
        for (int j2 = 0; j2 < 2; ++j2) {
            bf1[j2][0] = *(const bf16x8*)(ldsc + oBa + 16384 + j2 * 8192);
            bf1[j2][1] = *(const bf16x8*)(ldsc + oBb + 16384 + j2 * 8192);
        }
    };

    #define MFMA_CLUSTER(A, B, MH, NH)                                          \
        __builtin_amdgcn_s_setprio(1);                                          \
        _Pragma("unroll")                                                       \
        for (int ks = 0; ks < 2; ++ks)                                          \
            _Pragma("unroll")                                                   \
            for (int j = 0; j < 4; ++j)                                         \
                _Pragma("unroll")                                               \
                for (int j2 = 0; j2 < 2; ++j2)                                  \
                    acc[MH][NH][j][j2] = __builtin_amdgcn_mfma_f32_16x16x32_bf16(\
                        A[j][ks], B[j2][ks], acc[MH][NH][j][j2], 0, 0, 0);      \
        __builtin_amdgcn_s_setprio(0);

    // one K-tile (R11 structure)
    auto ktile = [&](auto SlC, auto St0, auto St2, auto RdN,
                     auto V1c, auto V3c, auto D0, auto D1) {
        constexpr int SL = SlC.value;
        // ---- p0 ----
        rd_bf1_cur();
        if constexpr (St0.value) { stA(ic<SL ^ 1>{}, ic<1>{}, D0);
                                   stB(ic<SL ^ 1>{}, ic<1>{}, D0); }
        MFMA_CLUSTER(afLo, bf0, 0, 0)
        // ---- p1 ----
        rd_afHi_cur();
        MFMA_CLUSTER(afLo, bf1, 0, 1)
        if constexpr (V1c.value == 4) asm volatile("s_waitcnt vmcnt(4)" ::: "memory");
        else if constexpr (V1c.value == 0) asm volatile("s_waitcnt vmcnt(0)" ::: "memory");
        __builtin_amdgcn_s_barrier();
        __builtin_amdgcn_sched_barrier(0);
        // ---- p2 ----
        if constexpr (RdN.value) rd_afLo_next();
        if constexpr (St2.value) { stA(SlC, ic<0>{}, D1);
                                   stB(SlC, ic<0>{}, D1); }
        MFMA_CLUSTER(afHi, bf1, 1, 1)
        // ---- p3 ----
        MFMA_CLUSTER(afHi, bf0, 1, 0)
        if constexpr (RdN.value) rd_bf0_next();
        if constexpr (V3c.value == 4) asm volatile("s_waitcnt vmcnt(4)" ::: "memory");
        else if constexpr (V3c.value == 0) asm volatile("s_waitcnt vmcnt(0)" ::: "memory");
        __builtin_amdgcn_s_barrier();
        __builtin_amdgcn_sched_barrier(0);
        // toggle read bases to the other slot
        oAa ^= SLOT_BYTES; oAb ^= SLOT_BYTES; oBa ^= SLOT_BYTES; oBb ^= SLOT_BYTES;
    };

    // prologue: stage tile0 full (8) + A0,B0(tile1) (4 = the steady "t-1.p2"
    // residue); vmcnt(4) drains tile0; barrier; read q0 frags of tile0.
    stA(ic<0>{}, ic<0>{}, ic<0>{});  stB(ic<0>{}, ic<0>{}, ic<0>{});
    stA(ic<0>{}, ic<1>{}, ic<0>{});  stB(ic<0>{}, ic<1>{}, ic<0>{});
    stA(ic<1>{}, ic<0>{}, ic<BK>{}); stB(ic<1>{}, ic<0>{}, ic<BK>{});
    asm volatile("s_waitcnt vmcnt(4)" ::: "memory");
    __builtin_amdgcn_s_barrier();
    __builtin_amdgcn_sched_barrier(0);
    {   // initial q0 fragments from slot 0 (bases currently at slot 0)
        #pragma unroll
        for (int j = 0; j < 4; ++j) {
            afLo[j][0] = *(const bf16x8*)(ldsc + oAa + j * 4096);
            afLo[j][1] = *(const bf16x8*)(ldsc + oAb + j * 4096);
        }
        #pragma unroll
        for (int j2 = 0; j2 < 2; ++j2) {
            bf0[j2][0] = *(const bf16x8*)(ldsc + oBa + j2 * 8192);
            bf0[j2][1] = *(const bf16x8*)(ldsc + oBb + j2 * 8192);
        }
    }

    // steady: 31 pairs = tiles 0..61
    for (int it = 0; it < 31; ++it) {
        ktile(ic<0>{}, bc<true>{}, bc<true>{}, bc<true>{},
              ic<4>{}, ic<4>{}, ic<BK>{}, ic<2 * BK>{});
        ktile(ic<1>{}, bc<true>{}, bc<true>{}, bc<true>{},
              ic<4>{}, ic<4>{}, ic<2 * BK>{}, ic<3 * BK>{});
        aT += 2 * BK;
        bT += 2 * BK;
    }
    // tile 62: stage A1B1(63) @p0 only; V1=4 drains A0B0(63) [from 61.p2];
    // V3=0 drains A1B1(63) before tile 63's reads.
    ktile(ic<0>{}, bc<true>{}, bc<false>{}, bc<true>{},
          ic<4>{}, ic<0>{}, ic<BK>{}, ic<0>{});
    // tile 63: no stages, no ahead-reads, no waits
    ktile(ic<1>{}, bc<false>{}, bc<false>{}, bc<false>{},
          ic<-1>{}, ic<-1>{}, ic<0>{}, ic<0>{});

    #undef MFMA_CLUSTER

    // epilogue: C/D layout col = lane&15 (out-dim), row = (lane>>4)*4 + rr (M)
    #pragma unroll
    for (int mh_ = 0; mh_ < 2; ++mh_)
        #pragma unroll
        for (int j = 0; j < 4; ++j)
            #pragma unroll
            for (int rr = 0; rr < 4; ++rr) {
                const int row = bm * BM + mh_ * 128 + j * 32 + wm * 16 + ((lane >> 4) << 2) + rr;
                float* orow = out + (size_t)row * K_TOT;
                #pragma unroll
                for (int nh_ = 0; nh_ < 2; ++nh_)
                    #pragma unroll
                    for (int j2 = 0; j2 < 2; ++j2) {
                        const int col = bn * BN + nh_ * 128 + j2 * 64 + wn * 16 + (lane & 15);
                        orow[col] = acc[mh_][nh_][j][j2][rr] + bias[col];
                    }
            }
}

extern "C" void kernel_launch(void* const* d_in, const int* in_sizes, int n_in,
                              void* d_out, int out_size, void* d_ws, size_t ws_size,
                              hipStream_t stream) {
    const float* x      = (const float*)d_in[0];
    const float* scales = (const float*)d_in[1];
    const float* zeros  = (const float*)d_in[2];
    const float* mu1    = (const float*)d_in[3];
    const float* mu2    = (const float*)d_in[4];
    const float* bias   = (const float*)d_in[5];
    const int*   wq     = (const int*)d_in[6];
    float* out = (float*)d_out;

    u16* xb = (u16*)d_ws;                                 // 64 MiB
    u16* wb = (u16*)d_ws + (size_t)M_TOT * N_TOT;         // 32 MiB

    prep_kernel<<<CVT_BLOCKS + DEQ_BLOCKS, 256, 0, stream>>>(
        x, xb, wq, scales, zeros, mu1, mu2, wb);
    gemm_kernel<<<(M_TOT / BM) * (K_TOT / BN), 512, 0, stream>>>(xb, wb, bias, out);
}